// Round 3
// 226.571 us; speedup vs baseline: 1.0191x; 1.0191x over previous
//
#include <hip/hip_runtime.h>

#define G_VOX  68921      // 41^3
#define GMAX   68920      // last valid element index
#define NSEG   272        // 272 segments of 256 elements (phase-shifted); last few are padding
#define MWORDS 2176       // 32-bit sphere-mask words (69632 bits)
#define NEGV (-1.0e9f)
#define VTH  (-1.0e8f)

__device__ __forceinline__ bool sphere_bit(const float* __restrict__ gxyz, int e) {
    if (e >= G_VOX) return false;
    float gx = gxyz[e * 3 + 0];
    float gy = gxyz[e * 3 + 1];
    float gz = gxyz[e * 3 + 2];
    float s  = __fadd_rn(__fadd_rn(__fmul_rn(gx, gx), __fmul_rn(gy, gy)),
                         __fmul_rn(gz, gz));
    return (__fsqrt_rn(s) <= 6.0f);   // bit-matches np.linalg.norm(grid_xyz) <= 6
}

// ---------------- Kernel 0: sphere word-mask ----------------
__global__ __launch_bounds__(256) void build_mask(
    const float* __restrict__ gxyz, unsigned int* __restrict__ mask)
{
    int idx = blockIdx.x * 256 + threadIdx.x;    // 0..69631
    unsigned long long bal = __ballot(sphere_bit(gxyz, idx));
    int lane = threadIdx.x & 63;
    if (lane == 0)       mask[idx >> 5] = (unsigned int)bal;
    else if (lane == 32) mask[idx >> 5] = (unsigned int)(bal >> 32);
}

// 8-lane segment scan: lanes l8=0..7 of a group cooperatively scan one 256-element
// segment s. Each lane: 8 independent UNCONDITIONAL float4 loads (tail clamped to
// an aligned in-bounds quad; mask bits are provably 0 beyond linear index 68080,
// so clamped garbage is never selected). Mask applied as selects, then a 3-level
// xor-shuffle reduce within the 8-lane group. All lanes return the group winner.
// NOTE: the 4-bit mask field straddles a word boundary when sh = (h+4*l8)&31 > 28
// (any h>0, l8=7) -> MUST use the two-word 64-bit extract. This was the R1 bug.
__device__ __forceinline__ void seg_scan8(
    const float* __restrict__ dens, const unsigned int* smask,
    int s, int h, int l8, int eclamp, float& bv, int& bi)
{
    const int ebase = h + 256 * s + 4 * l8;
    const int sh    = ebase & 31;          // 0..31: may straddle a word for h>0
    const int wd0   = ebase >> 5;
    bv = NEGV; bi = ebase;

    float4       dq[8];
    unsigned int bq[8];
    unsigned int wprev = smask[wd0];
    #pragma unroll
    for (int q = 0; q < 8; ++q) {
        const int e = ebase + 32 * q;
        const unsigned int wnext = smask[wd0 + q + 1];     // wd0+8 <= 2176 < MWORDS+2
        unsigned long long mw = ((unsigned long long)wnext << 32) | wprev;
        bq[q] = (unsigned int)(mw >> sh) & 0xFu;
        wprev = wnext;
        const int ec = (e + 3 <= GMAX) ? e : eclamp;       // branchless tail clamp
        dq[q] = *reinterpret_cast<const float4*>(dens + ec);
    }
    #pragma unroll
    for (int q = 0; q < 8; ++q) {
        const int e = ebase + 32 * q;
        float v0 = (bq[q] & 1u) ? dq[q].x : NEGV;
        float v1 = (bq[q] & 2u) ? dq[q].y : NEGV;
        float v2 = (bq[q] & 4u) ? dq[q].z : NEGV;
        float v3 = (bq[q] & 8u) ? dq[q].w : NEGV;
        if (v0 > bv) { bv = v0; bi = e;     }   // ascending e + strict > = first occurrence
        if (v1 > bv) { bv = v1; bi = e + 1; }
        if (v2 > bv) { bv = v2; bi = e + 2; }
        if (v3 > bv) { bv = v3; bi = e + 3; }
    }
    #pragma unroll
    for (int off = 4; off > 0; off >>= 1) {     // 3-level reduce within 8-lane group
        float ov = __shfl_xor(bv, off);
        int   oi = __shfl_xor(bi, off);
        if (ov > bv || (ov == bv && oi < bi)) { bv = ov; bi = oi; }
    }
}

// ---------------- Fused kernel: one density pass + K=4 pick/NMS, one block per nc ----------------
__global__ __launch_bounds__(512) void fused_peaks(
    const float* __restrict__ density,
    const float* __restrict__ gxyz,
    const unsigned int* __restrict__ maskg,
    const float* __restrict__ Rm, const float* __restrict__ tp,
    const float* __restrict__ nmask,
    float* __restrict__ out)
{
    __shared__ unsigned int smask[MWORDS + 2];   // +2: suppression's 64-bit clears touch wd+1
    __shared__ float sval[NSEG];
    __shared__ int   sidx[NSEG];
    __shared__ int   flag[NSEG];
    __shared__ int   list[104];
    __shared__ int   nlist;
    __shared__ float rv[8];
    __shared__ int   ri[8];
    __shared__ float pval[4];
    __shared__ int   pidx[4];
    __shared__ int   pki[4], pkj[4], pkk[4];

    const int tid  = threadIdx.x;
    const int nc   = blockIdx.x;                 // 0..511
    const int n    = nc >> 2;
    const int h    = (-nc) & 3;                  // phase: nc*68921 + h == 0 (mod 4)
    const int lane = tid & 63;
    const int w    = tid >> 6;                   // wave 0..7
    const int s8   = lane >> 3;                  // local segment in group 0..7
    const int l8   = lane & 7;                   // lane-in-segment 0..7
    const float* dens = density + (size_t)nc * G_VOX;
    const int eclamp = h + ((GMAX - 3 - h) & ~3);  // last aligned in-bounds quad start

    for (int i = tid; i < MWORDS + 2; i += 512) smask[i] = (i < MWORDS) ? maskg[i] : 0u;
    for (int i = tid; i < NSEG; i += 512) flag[i] = 0;
    __syncthreads();

    // ---- single density pass: wave w scans segment groups g = w, w+8, ... (34 groups of 8) ----
    for (int g = w; g < 34; g += 8) {
        const int s = g * 8 + s8;                // 0..271, each exactly once
        float bv; int bi;
        seg_scan8(dens, smask, s, h, l8, eclamp, bv, bi);
        if (l8 == 0) { sval[s] = bv; sidx[s] = bi; }
    }
    __syncthreads();

    // ---- K=4 rounds: table argmax + LDS-mask suppression + segment recompute ----
    for (int p = 0; p < 4; ++p) {
        float bv = -INFINITY;
        int   bi = 0x7FFFFFFF;
        if (tid < NSEG) { bv = sval[tid]; bi = sidx[tid]; }
        #pragma unroll
        for (int off = 32; off > 0; off >>= 1) {
            float ov = __shfl_down(bv, off);
            int   oi = __shfl_down(bi, off);
            if (ov > bv || (ov == bv && oi < bi)) { bv = ov; bi = oi; }
        }
        if (lane == 0) { rv[w] = bv; ri[w] = bi; }
        __syncthreads();
        if (w == 0) {
            bv = (lane < 8) ? rv[lane] : -INFINITY;
            bi = (lane < 8) ? ri[lane] : 0x7FFFFFFF;
            #pragma unroll
            for (int off = 4; off > 0; off >>= 1) {
                float ov = __shfl_down(bv, off);
                int   oi = __shfl_down(bi, off);
                if (ov > bv || (ov == bv && oi < bi)) { bv = ov; bi = oi; }
            }
            if (lane == 0) {
                pval[p] = bv;
                pidx[p] = bi;
                int pi = bi / 1681;
                int rr = bi - pi * 1681;
                int pj = rr / 41;
                pki[p] = pi; pkj[p] = pj; pkk[p] = rr - pj * 41;
                nlist = 0;
            }
        }
        __syncthreads();

        if (p < 3 && pval[p] > VTH) {
            // clear 7x7x7 Chebyshev cube bits in LDS mask; collect affected segments
            if (tid < 49) {
                int di = tid / 7 - 3, dj = tid % 7 - 3;
                int ii = pki[p] + di, jj = pkj[p] + dj;
                if (ii >= 0 && ii <= 40 && jj >= 0 && jj <= 40) {
                    int k0 = pkk[p] - 3; if (k0 < 0)  k0 = 0;
                    int k1 = pkk[p] + 3; if (k1 > 40) k1 = 40;
                    int b0  = ii * 1681 + jj * 41 + k0;
                    int cnt = k1 - k0 + 1;
                    unsigned long long m = ((1ull << cnt) - 1ull) << (b0 & 31);
                    int w0 = b0 >> 5;
                    atomicAnd(&smask[w0], ~(unsigned int)m);
                    unsigned int hi = (unsigned int)(m >> 32);
                    if (hi) atomicAnd(&smask[w0 + 1], ~hi);
                    // phase-shifted segment ids containing this run
                    int s0 = (b0 > h) ? (b0 - h) >> 8 : 0;
                    int s1 = (b0 + cnt - 1 > h) ? (b0 + cnt - 1 - h) >> 8 : 0;
                    if (atomicMax(&flag[s0], p + 1) < p + 1) {
                        int q = atomicAdd(&nlist, 1); list[q] = s0;
                    }
                    if (s1 != s0 && atomicMax(&flag[s1], p + 1) < p + 1) {
                        int q = atomicAdd(&nlist, 1); list[q] = s1;
                    }
                }
            }
            __syncthreads();
            // recompute flagged segments: one 8-lane group per list entry (64 segs/sweep)
            const int cnt = nlist;
            for (int base = 0; base < cnt; base += 64) {
                const int slot = base + w * 8 + s8;
                if (slot < cnt) {                // uniform within the 8-lane group
                    const int s = list[slot];
                    float bv2; int bi2;
                    seg_scan8(dens, smask, s, h, l8, eclamp, bv2, bi2);
                    if (l8 == 0) { sval[s] = bv2; sidx[s] = bi2; }
                }
            }
        }
        __syncthreads();
    }

    // ---- epilogue: one peak per thread ----
    if (tid < 4) {
        const int k   = tid;
        const float val = pval[k];
        const int   idx = pidx[k];
        const bool valid = val > VTH;
        float gx = 0.0f, gy = 0.0f, gz = 0.0f;
        if (valid) {
            gx = gxyz[idx * 3 + 0];
            gy = gxyz[idx * 3 + 1];
            gz = gxyz[idx * 3 + 2];
        }
        const float nm = nmask[n];
        const float* R = Rm + n * 9;
        const float* t = tp + n * 3;
        float wx = R[0] * gx + R[1] * gy + R[2] * gz + t[0];
        float wy = R[3] * gx + R[4] * gy + R[5] * gz + t[1];
        float wz = R[6] * gx + R[7] * gy + R[8] * gz + t[2];

        const size_t o3 = ((size_t)nc * 4 + k) * 3;
        out[o3 + 0] = gx * nm;                       // coords_local [1,128,4,4,3]
        out[o3 + 1] = gy * nm;
        out[o3 + 2] = gz * nm;
        out[6144 + o3 + 0] = wx * nm;                // coords_global
        out[6144 + o3 + 1] = wy * nm;
        out[6144 + o3 + 2] = wz * nm;
        const size_t o1 = (size_t)nc * 4 + k;
        out[12288 + o1] = (valid ? val : NEGV) * nm; // scores
        out[14336 + o1] = (valid && nm != 0.0f) ? 1.0f : 0.0f;  // mask
    }
}

extern "C" void kernel_launch(void* const* d_in, const int* in_sizes, int n_in,
                              void* d_out, int out_size, void* d_ws, size_t ws_size,
                              hipStream_t stream) {
    const float* density  = (const float*)d_in[0];  // [1,128,4,G] f32
    const float* grid_xyz = (const float*)d_in[1];  // [G,3] f32
    const float* Rm    = (const float*)d_in[4];     // [1,128,3,3] f32
    const float* tpos  = (const float*)d_in[5];     // [1,128,3] f32
    const float* nmask = (const float*)d_in[6];     // [1,128] f32
    float* out = (float*)d_out;                     // 16384 f32

    unsigned int* mask = (unsigned int*)d_ws;       // 8704 B

    build_mask<<<dim3(272), dim3(256), 0, stream>>>(grid_xyz, mask);
    fused_peaks<<<dim3(512), dim3(512), 0, stream>>>(density, grid_xyz, mask,
                                                     Rm, tpos, nmask, out);
}